// Round 1
// baseline (478.932 us; speedup 1.0000x reference)
//
#include <hip/hip_runtime.h>

// Problem constants (match reference)
constexpr int N    = 262144;   // rows
constexpr int C    = 1000;     // classes
constexpr int D4   = 64;       // FEAT_DIM / 4 float4s per row
constexpr int CPAD = 1024;     // padded class count (pow2 for scan)
constexpr float ALPHA = 0.5f;

// ---------------- workspace layout (d_ws) ----------------
// int counts [CPAD]
// int offs   [CPAD]
// int cursors[CPAD]
// int rowidx [N]
// total ~1.06 MB

__global__ void zero_counts_kernel(int* __restrict__ counts) {
    int t = blockIdx.x * blockDim.x + threadIdx.x;
    if (t < CPAD) counts[t] = 0;
}

__global__ void count_labels_kernel(const int* __restrict__ labels,
                                    int* __restrict__ counts) {
    int i = blockIdx.x * blockDim.x + threadIdx.x;
    if (i < N) atomicAdd(&counts[labels[i]], 1);
}

// One block of 1024 threads: Hillis-Steele inclusive scan -> exclusive offsets.
__global__ void scan_offsets_kernel(const int* __restrict__ counts,
                                    int* __restrict__ offs,
                                    int* __restrict__ cursors) {
    __shared__ int s[CPAD];
    int t = threadIdx.x;
    int v = counts[t];
    s[t] = v;
    __syncthreads();
    for (int off = 1; off < CPAD; off <<= 1) {
        int add = (t >= off) ? s[t - off] : 0;
        __syncthreads();
        s[t] += add;
        __syncthreads();
    }
    int excl = s[t] - v;   // exclusive prefix
    offs[t]    = excl;
    cursors[t] = excl;
}

__global__ void scatter_rows_kernel(const int* __restrict__ labels,
                                    int* __restrict__ cursors,
                                    int* __restrict__ rowidx) {
    int i = blockIdx.x * blockDim.x + threadIdx.x;
    if (i < N) {
        int pos = atomicAdd(&cursors[labels[i]], 1);
        rowidx[pos] = i;
    }
}

// One block per class; 4 waves; lane l covers dims [4l, 4l+3] via float4.
__global__ __launch_bounds__(256) void class_reduce_kernel(
        const float4* __restrict__ feat4,
        const float4* __restrict__ cen4,
        const int* __restrict__ offs,
        const int* __restrict__ counts,
        const int* __restrict__ rowidx,
        float4* __restrict__ out4) {
    int c     = blockIdx.x;
    int start = offs[c];
    int cnt   = counts[c];
    int wave  = threadIdx.x >> 6;
    int lane  = threadIdx.x & 63;
    int end   = start + cnt;

    float a0x = 0.f, a0y = 0.f, a0z = 0.f, a0w = 0.f;
    float a1x = 0.f, a1y = 0.f, a1z = 0.f, a1w = 0.f;
    float a2x = 0.f, a2y = 0.f, a2z = 0.f, a2w = 0.f;
    float a3x = 0.f, a3y = 0.f, a3z = 0.f, a3w = 0.f;

    int j = start + wave;               // wave-strided rows (stride 4)
    // 4-deep unroll for memory-level parallelism
    for (; j + 12 < end; j += 16) {
        int r0 = rowidx[j];
        int r1 = rowidx[j + 4];
        int r2 = rowidx[j + 8];
        int r3 = rowidx[j + 12];
        float4 v0 = feat4[(long)r0 * D4 + lane];
        float4 v1 = feat4[(long)r1 * D4 + lane];
        float4 v2 = feat4[(long)r2 * D4 + lane];
        float4 v3 = feat4[(long)r3 * D4 + lane];
        a0x += v0.x; a0y += v0.y; a0z += v0.z; a0w += v0.w;
        a1x += v1.x; a1y += v1.y; a1z += v1.z; a1w += v1.w;
        a2x += v2.x; a2y += v2.y; a2z += v2.z; a2w += v2.w;
        a3x += v3.x; a3y += v3.y; a3z += v3.z; a3w += v3.w;
    }
    for (; j < end; j += 4) {
        int r = rowidx[j];
        float4 v = feat4[(long)r * D4 + lane];
        a0x += v.x; a0y += v.y; a0z += v.z; a0w += v.w;
    }
    a0x += a1x + a2x + a3x;
    a0y += a1y + a2y + a3y;
    a0z += a1z + a2z + a3z;
    a0w += a1w + a2w + a3w;

    __shared__ float red[4][64][4];
    red[wave][lane][0] = a0x;
    red[wave][lane][1] = a0y;
    red[wave][lane][2] = a0z;
    red[wave][lane][3] = a0w;
    __syncthreads();

    if (wave == 0) {
        float sx = red[0][lane][0] + red[1][lane][0] + red[2][lane][0] + red[3][lane][0];
        float sy = red[0][lane][1] + red[1][lane][1] + red[2][lane][1] + red[3][lane][1];
        float sz = red[0][lane][2] + red[1][lane][2] + red[2][lane][2] + red[3][lane][2];
        float sw = red[0][lane][3] + red[1][lane][3] + red[2][lane][3] + red[3][lane][3];

        float4 cen = cen4[c * D4 + lane];
        float4 o;
        if (cnt > 0) {
            float s = ALPHA / (float)cnt;      // alpha * mean
            o.x = (1.0f - ALPHA) * cen.x + sx * s;
            o.y = (1.0f - ALPHA) * cen.y + sy * s;
            o.z = (1.0f - ALPHA) * cen.z + sz * s;
            o.w = (1.0f - ALPHA) * cen.w + sw * s;
        } else {
            o = cen;
        }
        out4[c * D4 + lane] = o;
    }
}

extern "C" void kernel_launch(void* const* d_in, const int* in_sizes, int n_in,
                              void* d_out, int out_size, void* d_ws, size_t ws_size,
                              hipStream_t stream) {
    const float4* feat4  = (const float4*)d_in[0];
    const int*    labels = (const int*)d_in[1];
    const float4* cen4   = (const float4*)d_in[2];
    float4*       out4   = (float4*)d_out;

    int* counts  = (int*)d_ws;
    int* offs    = counts + CPAD;
    int* cursors = offs + CPAD;
    int* rowidx  = cursors + CPAD;

    zero_counts_kernel<<<CPAD / 256, 256, 0, stream>>>(counts);
    count_labels_kernel<<<N / 256, 256, 0, stream>>>(labels, counts);
    scan_offsets_kernel<<<1, CPAD, 0, stream>>>(counts, offs, cursors);
    scatter_rows_kernel<<<N / 256, 256, 0, stream>>>(labels, cursors, rowidx);
    class_reduce_kernel<<<C, 256, 0, stream>>>(feat4, cen4, offs, counts, rowidx, out4);
}

// Round 3
// 363.219 us; speedup vs baseline: 1.3186x; 1.3186x over previous
//
#include <hip/hip_runtime.h>

// Problem constants (match reference)
constexpr int N    = 262144;   // rows
constexpr int C    = 1000;     // classes
constexpr int D4   = 64;       // FEAT_DIM / 4 float4s per row
constexpr int CPAD = 1024;     // padded class count (pow2 for scan/LDS)
constexpr int NB   = 64;       // histogram/scatter blocks
constexpr int ROWS_PER_B = N / NB;  // 4096
constexpr float ALPHA = 0.5f;

// Native vector type for nontemporal builtins (HIP_vector_type is rejected).
typedef float vfloat4 __attribute__((ext_vector_type(4)));

// ---------------- workspace layout (d_ws) ----------------
// int hist       [NB][CPAD]   256 KB  (fully written by hist_kernel)
// int counts     [CPAD]
// int offs       [CPAD]
// int blockcursor[NB][CPAD]   256 KB
// int rowidx     [N]          1 MB
// No buffer is read before being fully written -> no zero-init needed.

// 64 blocks x 256 threads; block b histograms rows [b*4096, (b+1)*4096).
// LDS atomics only; plain global stores of the per-block histogram.
__global__ __launch_bounds__(256) void hist_kernel(
        const int* __restrict__ labels, int* __restrict__ hist) {
    __shared__ int h[CPAD];
    int t = threadIdx.x;
    for (int i = t; i < CPAD; i += 256) h[i] = 0;
    __syncthreads();
    int base = blockIdx.x * ROWS_PER_B;
    for (int i = t; i < ROWS_PER_B; i += 256)
        atomicAdd(&h[labels[base + i]], 1);
    __syncthreads();
    int* out = hist + blockIdx.x * CPAD;
    for (int i = t; i < CPAD; i += 256) out[i] = h[i];
}

// One block of 1024 threads (thread t = class t):
//  counts[t] = sum_b hist[b][t]; offs = exclusive scan(counts);
//  blockcursor[b][t] = offs[t] + prefix_b(hist[b][t]).
__global__ __launch_bounds__(1024) void scan_kernel(
        const int* __restrict__ hist,
        int* __restrict__ counts,
        int* __restrict__ offs,
        int* __restrict__ blockcursor) {
    __shared__ int s[CPAD];
    int t = threadIdx.x;
    int total = 0;
    #pragma unroll 8
    for (int b = 0; b < NB; ++b) total += hist[b * CPAD + t];
    counts[t] = total;
    s[t] = total;
    __syncthreads();
    for (int off = 1; off < CPAD; off <<= 1) {
        int add = (t >= off) ? s[t - off] : 0;
        __syncthreads();
        s[t] += add;
        __syncthreads();
    }
    int run = s[t] - total;   // exclusive prefix
    offs[t] = run;
    for (int b = 0; b < NB; ++b) {
        blockcursor[b * CPAD + t] = run;
        run += hist[b * CPAD + t];
    }
}

// 64 blocks x 256 threads; LDS-private cursors per block -> zero global atomics.
__global__ __launch_bounds__(256) void scatter_kernel(
        const int* __restrict__ labels,
        const int* __restrict__ blockcursor,
        int* __restrict__ rowidx) {
    __shared__ int cur[CPAD];
    int t = threadIdx.x;
    const int* bc = blockcursor + blockIdx.x * CPAD;
    for (int i = t; i < CPAD; i += 256) cur[i] = bc[i];
    __syncthreads();
    int base = blockIdx.x * ROWS_PER_B;
    for (int i = t; i < ROWS_PER_B; i += 256) {
        int row = base + i;
        int pos = atomicAdd(&cur[labels[row]], 1);
        rowidx[pos] = row;
    }
}

// One block per class; 4 waves; lane l covers dims [4l,4l+3] via float4.
// 8 independent nontemporal 1KB row-gathers in flight per wave.
__global__ __launch_bounds__(256) void class_reduce_kernel(
        const vfloat4* __restrict__ feat4,
        const float4* __restrict__ cen4,
        const int* __restrict__ offs,
        const int* __restrict__ counts,
        const int* __restrict__ rowidx,
        float4* __restrict__ out4) {
    int c     = blockIdx.x;
    int start = offs[c];
    int cnt   = counts[c];
    int wave  = threadIdx.x >> 6;
    int lane  = threadIdx.x & 63;
    int end   = start + cnt;

    vfloat4 acc[8];
    #pragma unroll
    for (int u = 0; u < 8; ++u) acc[u] = (vfloat4)0.f;

    int j = start + wave;               // wave-strided rows (stride 4)
    // 8-deep unroll: 8 independent gathers in flight per wave
    for (; j + 28 < end; j += 32) {
        int r[8];
        #pragma unroll
        for (int u = 0; u < 8; ++u) r[u] = rowidx[j + 4 * u];
        #pragma unroll
        for (int u = 0; u < 8; ++u) {
            vfloat4 v = __builtin_nontemporal_load(&feat4[(long)r[u] * D4 + lane]);
            acc[u] += v;
        }
    }
    for (; j < end; j += 4) {
        int r = rowidx[j];
        vfloat4 v = __builtin_nontemporal_load(&feat4[(long)r * D4 + lane]);
        acc[0] += v;
    }
    #pragma unroll
    for (int u = 1; u < 8; ++u) acc[0] += acc[u];

    __shared__ float red[4][64][4];
    red[wave][lane][0] = acc[0].x;
    red[wave][lane][1] = acc[0].y;
    red[wave][lane][2] = acc[0].z;
    red[wave][lane][3] = acc[0].w;
    __syncthreads();

    if (wave == 0) {
        float sx = red[0][lane][0] + red[1][lane][0] + red[2][lane][0] + red[3][lane][0];
        float sy = red[0][lane][1] + red[1][lane][1] + red[2][lane][1] + red[3][lane][1];
        float sz = red[0][lane][2] + red[1][lane][2] + red[2][lane][2] + red[3][lane][2];
        float sw = red[0][lane][3] + red[1][lane][3] + red[2][lane][3] + red[3][lane][3];

        float4 cen = cen4[c * D4 + lane];
        float4 o;
        if (cnt > 0) {
            float s = ALPHA / (float)cnt;      // alpha * mean
            o.x = (1.0f - ALPHA) * cen.x + sx * s;
            o.y = (1.0f - ALPHA) * cen.y + sy * s;
            o.z = (1.0f - ALPHA) * cen.z + sz * s;
            o.w = (1.0f - ALPHA) * cen.w + sw * s;
        } else {
            o = cen;
        }
        out4[c * D4 + lane] = o;
    }
}

extern "C" void kernel_launch(void* const* d_in, const int* in_sizes, int n_in,
                              void* d_out, int out_size, void* d_ws, size_t ws_size,
                              hipStream_t stream) {
    const vfloat4* feat4  = (const vfloat4*)d_in[0];
    const int*     labels = (const int*)d_in[1];
    const float4*  cen4   = (const float4*)d_in[2];
    float4*        out4   = (float4*)d_out;

    int* hist        = (int*)d_ws;
    int* counts      = hist + NB * CPAD;
    int* offs        = counts + CPAD;
    int* blockcursor = offs + CPAD;
    int* rowidx      = blockcursor + NB * CPAD;

    hist_kernel<<<NB, 256, 0, stream>>>(labels, hist);
    scan_kernel<<<1, CPAD, 0, stream>>>(hist, counts, offs, blockcursor);
    scatter_kernel<<<NB, 256, 0, stream>>>(labels, blockcursor, rowidx);
    class_reduce_kernel<<<C, 256, 0, stream>>>(feat4, cen4, offs, counts, rowidx, out4);
}